// Round 11
// baseline (101.961 us; speedup 1.0000x reference)
//
#include <hip/hip_runtime.h>

#define B_DIM   16384
#define T_DIM   50
#define F_DIM   128
#define NSPLIT  63
#define LEAVES  64
#define DEPTHM1 6
#define PROB_SZ (B_DIM * T_DIM * 2)

#define WPB    4                   // waves per block
#define BLOCK  (WPB * 64)          // 256
#define GRID   1280                // 5 blocks/CU x 256 CU: fully resident, no rounds
#define STRIDE (GRID * WPB)        // 5120 global waves; each does 3-4 b's

typedef float vf2 __attribute__((ext_vector_type(2)));

// Kernel 1: one-hot masks -> u8 feature index, padded rows [T_DIM][64].
__global__ __launch_bounds__(256)
void build_tables(const float* __restrict__ masks, unsigned char* __restrict__ idx) {
    __shared__ float m_l[F_DIM * NSPLIT];   // 32.2 KB
    const int t = blockIdx.x;
    const float* src = masks + (size_t)t * (F_DIM * NSPLIT);
    for (int i = threadIdx.x; i < F_DIM * NSPLIT; i += 256) m_l[i] = src[i];
    __syncthreads();
    const int n = threadIdx.x;
    if (n < NSPLIT) {
        int fi = 0;
        for (int f = 0; f < F_DIM; ++f)
            if (m_l[f * NSPLIT + n] != 0.f) fi = f;
        idx[t * 64 + n] = (unsigned char)fi;
    }
}

// waves_per_eu(4,5): pin allocator to ~102-VGPR regime (R8 lesson: without a
// max it squeezed to 64 VGPRs chasing 8 waves/EU and spilled to scratch).
__global__ __launch_bounds__(BLOCK)
__attribute__((amdgpu_waves_per_eu(4, 5)))
void forest_kernel(const float* __restrict__ x, const float* __restrict__ pi,
                   const unsigned char* __restrict__ tbl, float* __restrict__ out) {
    __shared__ float xs[WPB][F_DIM];        //  2.0 KB (wave-private rows)
    __shared__ vf2   pi_p[LEAVES * T_DIM];  // 25.6 KB: [l][t]=(pi[t,l,0],pi[t,l,1])
    // total 27.6 KB -> 5 blocks/CU

    const int tid  = threadIdx.x;
    const int w    = tid >> 6;
    const int lane = tid & 63;
    const int t    = lane;                  // lanes 50..63 idle in compute

    // per-lane idx row -> 16 u32 registers (once per block; 3.2KB table is
    // L1/L2-resident; removes 63 ds_read_u8 from every b-iteration)
    unsigned int warr[16];
    {
        const uint4* row = (const uint4*)(tbl + (size_t)((t < T_DIM) ? t : 0) * 64);
        uint4 r0 = row[0], r1 = row[1], r2 = row[2], r3 = row[3];
        *(uint4*)&warr[0]  = r0; *(uint4*)&warr[4]  = r1;
        *(uint4*)&warr[8]  = r2; *(uint4*)&warr[12] = r3;
    }
#define IDX(k) ((int)((warr[(k) >> 2] >> (((k) & 3) * 8)) & 127u))

    // pi transpose-stage: global float2 index i = t*64 + l -> LDS [l*50 + t]
    for (int i = tid; i < T_DIM * LEAVES; i += BLOCK) {
        int t2 = i >> 6, l2 = i & 63;
        vf2 q = ((const vf2*)pi)[i];
        pi_p[l2 * T_DIM + t2] = q;
    }
    __syncthreads();   // only block-wide barrier; waves free-run afterwards

    const int gw = blockIdx.x * WPB + w;    // global wave id, 0..5119
    float* xw = xs[w];

    // prologue: first x row -> regs (all 64 lanes, coalesced 512B)
    vf2 xreg = *(const vf2*)(x + (size_t)gw * F_DIM + 2 * lane);

    for (int b = gw; b < B_DIM; b += STRIDE) {
        // wave-private LDS write; same-wave DS ops are in-order vs prior reads
        *(vf2*)(&xw[2 * lane]) = xreg;

        float mu[LEAVES / 2];       // levels 0..4 only (32 regs)
        float p0 = 0.f, p1 = 0.f;
        float* dstb = out + PROB_SZ + (size_t)b * (LEAVES * T_DIM) + t;

        if (t < T_DIM) {
            mu[0] = 1.f;
            int begin = 0;
            // levels 0..4: pure compute, builds mu[0..31]
#pragma unroll
            for (int level = 0; level < DEPTHM1 - 1; ++level) {
                const int width = 1 << level;
#pragma unroll
                for (int i = width - 1; i >= 0; --i) {
                    const int fi = IDX(begin + i);              // v_bfe (no LDS)
                    float xv = xw[fi];                          // ds_read_b32 gather
                    float e  = __expf(-xv);
                    float d  = __builtin_amdgcn_rcpf(1.f + e);
                    float m  = mu[i];
                    mu[2 * i]     = m * d;
                    mu[2 * i + 1] = m - mu[2 * i];
                }
                begin += width;
            }
        }

        // prefetch next x row NOW so HBM latency hides under the whole
        // fused store/pi loop (~1000+ cyc), not just the final prob store
        const int bn = b + STRIDE;
        if (bn < B_DIM)
            xreg = *(const vf2*)(x + (size_t)bn * F_DIM + 2 * lane);

        if (t < T_DIM) {
            const vf2* pp = &pi_p[t];
            // level 5 fused with probs-store + pi-reduction (anti-convoy)
#pragma unroll
            for (int i = 31; i >= 0; --i) {
                const int fi = IDX(31 + i);
                float xv = xw[fi];
                float e  = __expf(-xv);
                float d  = __builtin_amdgcn_rcpf(1.f + e);
                float m  = mu[i];
                float a  = m * d;
                float c2 = m - a;
                dstb[(2 * i)     * T_DIM] = a;     // contiguous 200B run/inst
                dstb[(2 * i + 1) * T_DIM] = c2;
                vf2 q0 = pp[(2 * i)     * T_DIM];  // conflict-free ds_read_b64
                vf2 q1 = pp[(2 * i + 1) * T_DIM];
                p0 += a * q0.x + c2 * q1.x;
                p1 += a * q0.y + c2 * q1.y;
            }
            ((vf2*)out)[b * T_DIM + t] = (vf2){p0, p1};
        }
    }
#undef IDX
}

extern "C" void kernel_launch(void* const* d_in, const int* in_sizes, int n_in,
                              void* d_out, int out_size, void* d_ws, size_t ws_size,
                              hipStream_t stream) {
    const float* x     = (const float*)d_in[0];
    const float* masks = (const float*)d_in[1];
    const float* pi    = (const float*)d_in[2];

    unsigned char* tbl = (unsigned char*)d_ws;
    float* out = (float*)d_out;

    build_tables<<<T_DIM, 256, 0, stream>>>(masks, tbl);
    forest_kernel<<<GRID, BLOCK, 0, stream>>>(x, pi, tbl, out);
}

// Round 12
// 98.169 us; speedup vs baseline: 1.0386x; 1.0386x over previous
//
#include <hip/hip_runtime.h>

#define B_DIM   16384
#define T_DIM   50
#define F_DIM   128
#define NSPLIT  63
#define LEAVES  64
#define DEPTHM1 6
#define PROB_SZ (B_DIM * T_DIM * 2)

#define WPB    4                   // waves per block
#define BLOCK  (WPB * 64)          // 256
#define GRID   1024                // 4 blocks/CU x 256 CU: resident at 4 OR 5 blocks/CU
#define NWAVES (GRID * WPB)        // 4096 waves; each owns exactly 4 contiguous b's
#define BPW    (B_DIM / NWAVES)    // 4

typedef float vf2 __attribute__((ext_vector_type(2)));

// Kernel 1: one-hot masks -> u8 feature index, padded rows [T_DIM][64].
__global__ __launch_bounds__(256)
void build_tables(const float* __restrict__ masks, unsigned char* __restrict__ idx) {
    __shared__ float m_l[F_DIM * NSPLIT];   // 32.2 KB
    const int t = blockIdx.x;
    const float* src = masks + (size_t)t * (F_DIM * NSPLIT);
    for (int i = threadIdx.x; i < F_DIM * NSPLIT; i += 256) m_l[i] = src[i];
    __syncthreads();
    const int n = threadIdx.x;
    if (n < NSPLIT) {
        int fi = 0;
        for (int f = 0; f < F_DIM; ++f)
            if (m_l[f * NSPLIT + n] != 0.f) fi = f;
        idx[t * 64 + n] = (unsigned char)fi;
    }
}

// waves_per_eu(4,4): allocator may use up to 128 VGPRs (no 5-wave squeeze ->
// no spills, R8 lesson) and we assume only 4 blocks/CU residency (R10 lesson:
// assuming 5 left 256 straggler blocks -> ~2x makespan).
__global__ __launch_bounds__(BLOCK)
__attribute__((amdgpu_waves_per_eu(4, 4)))
void forest_kernel(const float* __restrict__ x, const float* __restrict__ pi,
                   const unsigned char* __restrict__ tbl, float* __restrict__ out) {
    __shared__ float xs[WPB][F_DIM];        //  2.0 KB (wave-private rows)
    __shared__ vf2   pi_p[LEAVES * T_DIM];  // 25.6 KB: [l][t]=(pi[t,l,0],pi[t,l,1])
    // total 27.6 KB

    const int tid  = threadIdx.x;
    const int w    = tid >> 6;
    const int lane = tid & 63;
    const int t    = lane;                  // lanes 50..63 idle in compute

    // per-lane idx row -> 16 u32 registers (once; 3.2KB table L1/L2-resident)
    unsigned int warr[16];
    {
        const uint4* row = (const uint4*)(tbl + (size_t)((t < T_DIM) ? t : 0) * 64);
        uint4 r0 = row[0], r1 = row[1], r2 = row[2], r3 = row[3];
        *(uint4*)&warr[0]  = r0; *(uint4*)&warr[4]  = r1;
        *(uint4*)&warr[8]  = r2; *(uint4*)&warr[12] = r3;
    }
#define IDX(k) ((int)((warr[(k) >> 2] >> (((k) & 3) * 8)) & 127u))

    // pi transpose-stage: global float2 index i = t*64 + l -> LDS [l*50 + t]
    for (int i = tid; i < T_DIM * LEAVES; i += BLOCK) {
        int t2 = i >> 6, l2 = i & 63;
        vf2 q = ((const vf2*)pi)[i];
        pi_p[l2 * T_DIM + t2] = q;
    }
    __syncthreads();   // only block-wide barrier; waves free-run afterwards

    const int gw = blockIdx.x * WPB + w;    // global wave id, 0..4095
    const int b0 = gw * BPW;                // contiguous 4-b range per wave
    float* xw = xs[w];

    // prologue: first x row -> regs (all 64 lanes, coalesced 512B)
    vf2 xreg = *(const vf2*)(x + (size_t)b0 * F_DIM + 2 * lane);

    for (int it = 0; it < BPW; ++it) {
        const int b = b0 + it;

        // wave-private LDS write; same-wave DS ops are in-order vs prior reads
        *(vf2*)(&xw[2 * lane]) = xreg;

        float mu[LEAVES / 2];       // levels 0..4 only (32 regs)
        float p0 = 0.f, p1 = 0.f;
        float* dstb = out + PROB_SZ + (size_t)b * (LEAVES * T_DIM) + t;

        if (t < T_DIM) {
            mu[0] = 1.f;
            int begin = 0;
            // levels 0..4: pure compute, builds mu[0..31]
#pragma unroll
            for (int level = 0; level < DEPTHM1 - 1; ++level) {
                const int width = 1 << level;
#pragma unroll
                for (int i = width - 1; i >= 0; --i) {
                    const int fi = IDX(begin + i);              // v_bfe (no LDS)
                    float xv = xw[fi];                          // ds_read_b32 gather
                    float e  = __expf(-xv);
                    float d  = __builtin_amdgcn_rcpf(1.f + e);
                    float m  = mu[i];
                    mu[2 * i]     = m * d;
                    mu[2 * i + 1] = m - mu[2 * i];
                }
                begin += width;
            }
        }

        // prefetch next x row BEFORE the store loop: with ~65 stores issued
        // after it, the consumer's wait clamps at vmcnt(63) -> drains only
        // ~2 stores (vs near-full drain if issued after the stores)
        if (it + 1 < BPW)
            xreg = *(const vf2*)(x + (size_t)(b + 1) * F_DIM + 2 * lane);

        if (t < T_DIM) {
            const vf2* pp = &pi_p[t];
            // level 5 fused with probs-store + pi-reduction (anti-convoy)
#pragma unroll
            for (int i = 31; i >= 0; --i) {
                const int fi = IDX(31 + i);
                float xv = xw[fi];
                float e  = __expf(-xv);
                float d  = __builtin_amdgcn_rcpf(1.f + e);
                float m  = mu[i];
                float a  = m * d;
                float c2 = m - a;
                dstb[(2 * i)     * T_DIM] = a;     // contiguous 200B run/inst
                dstb[(2 * i + 1) * T_DIM] = c2;
                vf2 q0 = pp[(2 * i)     * T_DIM];  // conflict-free ds_read_b64
                vf2 q1 = pp[(2 * i + 1) * T_DIM];
                p0 += a * q0.x + c2 * q1.x;
                p1 += a * q0.y + c2 * q1.y;
            }
            ((vf2*)out)[b * T_DIM + t] = (vf2){p0, p1};
        }
    }
#undef IDX
}

extern "C" void kernel_launch(void* const* d_in, const int* in_sizes, int n_in,
                              void* d_out, int out_size, void* d_ws, size_t ws_size,
                              hipStream_t stream) {
    const float* x     = (const float*)d_in[0];
    const float* masks = (const float*)d_in[1];
    const float* pi    = (const float*)d_in[2];

    unsigned char* tbl = (unsigned char*)d_ws;
    float* out = (float*)d_out;

    build_tables<<<T_DIM, 256, 0, stream>>>(masks, tbl);
    forest_kernel<<<GRID, BLOCK, 0, stream>>>(x, pi, tbl, out);
}

// Round 13
// 50.340 us; speedup vs baseline: 2.0254x; 1.9501x over previous
//
#include <hip/hip_runtime.h>

#define B_DIM   16384
#define T_DIM   50
#define F_DIM   128
#define NSPLIT  63
#define LEAVES  64
#define DEPTHM1 6
#define PROB_SZ (B_DIM * T_DIM * 2)

#define WPB   4                    // waves per block
#define BLOCK (WPB * 64)           // 256
#define IT    2                    // b's per wave — VERIFIED: IT/BPW=4 and
#define GRID  (B_DIM / (WPB * IT)) // 2048         persistent variants = ~2x (R8/R10/R11)

typedef float vf2 __attribute__((ext_vector_type(2)));

// Kernel 1: one-hot masks -> u8 feature index, padded rows [T_DIM][64].
__global__ __launch_bounds__(256)
void build_tables(const float* __restrict__ masks, unsigned char* __restrict__ idx) {
    __shared__ float m_l[F_DIM * NSPLIT];   // 32.2 KB
    const int t = blockIdx.x;
    const float* src = masks + (size_t)t * (F_DIM * NSPLIT);
    for (int i = threadIdx.x; i < F_DIM * NSPLIT; i += 256) m_l[i] = src[i];
    __syncthreads();
    const int n = threadIdx.x;
    if (n < NSPLIT) {
        int fi = 0;
        for (int f = 0; f < F_DIM; ++f)
            if (m_l[f * NSPLIT + n] != 0.f) fi = f;
        idx[t * 64 + n] = (unsigned char)fi;
    }
}

// waves_per_eu(4,5): pin the register allocator to the ~102-VGPR regime.
// R8 lesson: without the max, the compiler squeezed to 64 VGPRs (8 waves/EU)
// and spilled warr[]+mu[] to scratch (+71MB fetch, +43MB write, 2x time).
__global__ __launch_bounds__(BLOCK)
__attribute__((amdgpu_waves_per_eu(4, 5)))
void forest_kernel(const float* __restrict__ x, const float* __restrict__ pi,
                   const unsigned char* __restrict__ tbl, float* __restrict__ out) {
    __shared__ float xs[WPB][F_DIM];        //  2.0 KB (wave-private rows)
    __shared__ vf2   pi_p[LEAVES * T_DIM];  // 25.6 KB: [l][t]=(pi[t,l,0],pi[t,l,1])
    // total 27.6 KB -> 5 blocks/CU

    const int tid  = threadIdx.x;
    const int w    = tid >> 6;
    const int lane = tid & 63;
    const int t    = lane;                  // lanes 50..63 idle in compute

    // per-lane idx row -> 16 u32 registers (once per wave; table is 3.2KB,
    // L1/L2-resident; removes 63 ds_read_u8 from every b-iteration)
    unsigned int warr[16];
    {
        const uint4* row = (const uint4*)(tbl + (size_t)((t < T_DIM) ? t : 0) * 64);
        uint4 r0 = row[0], r1 = row[1], r2 = row[2], r3 = row[3];
        *(uint4*)&warr[0]  = r0; *(uint4*)&warr[4]  = r1;
        *(uint4*)&warr[8]  = r2; *(uint4*)&warr[12] = r3;
    }
#define IDX(k) ((int)((warr[(k) >> 2] >> (((k) & 3) * 8)) & 127u))

    // pi transpose-stage: global float2 index i = t*64 + l -> LDS [l*50 + t]
    for (int i = tid; i < T_DIM * LEAVES; i += BLOCK) {
        int t2 = i >> 6, l2 = i & 63;
        vf2 q = ((const vf2*)pi)[i];
        pi_p[l2 * T_DIM + t2] = q;
    }
    __syncthreads();   // only block-wide barrier; waves free-run afterwards

    const int bw0 = (blockIdx.x * WPB + w) * IT;
    float* xw = xs[w];

    // prologue: first x row -> regs (all 64 lanes, coalesced 512B)
    vf2 xreg = *(const vf2*)(x + (size_t)bw0 * F_DIM + 2 * lane);

    for (int it = 0; it < IT; ++it) {
        const int b = bw0 + it;

        // wave-private LDS write; DS ops in-order vs previous iter's reads
        *(vf2*)(&xw[2 * lane]) = xreg;

        float mu[LEAVES / 2];       // levels 0..4 only (32 regs)
        float p0 = 0.f, p1 = 0.f;
        float* dstb = out + PROB_SZ + (size_t)b * (LEAVES * T_DIM) + t;

        if (t < T_DIM) {
            const vf2* pp = &pi_p[t];

            mu[0] = 1.f;
            int begin = 0;
            // levels 0..4: pure compute, builds mu[0..31]
#pragma unroll
            for (int level = 0; level < DEPTHM1 - 1; ++level) {
                const int width = 1 << level;
#pragma unroll
                for (int i = width - 1; i >= 0; --i) {
                    const int fi = IDX(begin + i);              // v_bfe (no LDS)
                    float xv = xw[fi];                          // ds_read_b32 gather
                    float e  = __expf(-xv);
                    float d  = __builtin_amdgcn_rcpf(1.f + e);
                    float m  = mu[i];
                    mu[2 * i]     = m * d;
                    mu[2 * i + 1] = m - mu[2 * i];
                }
                begin += width;
            }
            // level 5 fused with probs-store + pi-reduction (anti-convoy)
#pragma unroll
            for (int i = 31; i >= 0; --i) {
                const int fi = IDX(31 + i);
                float xv = xw[fi];
                float e  = __expf(-xv);
                float d  = __builtin_amdgcn_rcpf(1.f + e);
                float m  = mu[i];
                float a  = m * d;
                float c2 = m - a;
                dstb[(2 * i)     * T_DIM] = a;     // contiguous 200B run/inst
                dstb[(2 * i + 1) * T_DIM] = c2;
                vf2 q0 = pp[(2 * i)     * T_DIM];  // conflict-free ds_read_b64
                vf2 q1 = pp[(2 * i + 1) * T_DIM];
                p0 += a * q0.x + c2 * q1.x;
                p1 += a * q0.y + c2 * q1.y;
            }
        }

        // prefetch next x row while stores drain (VERIFIED position: moving
        // this before the store loop correlated with the 2x regressions)
        if (it + 1 < IT)
            xreg = *(const vf2*)(x + (size_t)(b + 1) * F_DIM + 2 * lane);

        if (t < T_DIM)
            ((vf2*)out)[b * T_DIM + t] = (vf2){p0, p1};
    }
#undef IDX
}

extern "C" void kernel_launch(void* const* d_in, const int* in_sizes, int n_in,
                              void* d_out, int out_size, void* d_ws, size_t ws_size,
                              hipStream_t stream) {
    const float* x     = (const float*)d_in[0];
    const float* masks = (const float*)d_in[1];
    const float* pi    = (const float*)d_in[2];

    unsigned char* tbl = (unsigned char*)d_ws;
    float* out = (float*)d_out;

    build_tables<<<T_DIM, 256, 0, stream>>>(masks, tbl);
    forest_kernel<<<GRID, BLOCK, 0, stream>>>(x, pi, tbl, out);
}